// Round 1
// baseline (10379.271 us; speedup 1.0000x reference)
//
#include <hip/hip_runtime.h>
#include <math.h>

#define SS 512
#define BB 64
#define EE 256
#define HH 512
#define NT 9

// ws layout (float32 elements):
//  hs   : (SS+1)*BB*HH  at 0            (slot 0 = h_{-1} = zeros)
//  c    : BB*HH         at C_OFF
//  em   : SS*BB*NT      at EM_OFF
//  num  : 64            at NUM_OFF
//  norm : 64            at NORM_OFF
#define HS_ELEMS ((size_t)(SS + 1) * BB * HH)
#define C_OFF    HS_ELEMS
#define EM_OFF   (C_OFF + (size_t)BB * HH)
#define NUM_OFF  (EM_OFF + (size_t)SS * BB * NT)
#define NORM_OFF (NUM_OFF + 64)

__global__ __launch_bounds__(256) void init_state(float* __restrict__ ws) {
    int idx = blockIdx.x * 256 + threadIdx.x;   // 65536 total
    if (idx < BB * HH) {
        ws[idx] = 0.0f;                          // hs slot 0
    } else {
        ws[C_OFF + (idx - BB * HH)] = 0.0f;      // c state
    }
}

// 256 WGs = 32 unit-slices x 8 batch-groups; 512 threads = 8 waves.
// Wave w handles local gate-rows l = w*8 .. w*8+7 (l = gate*16 + unit_local).
// Lane L: b_l = L&7 (batch within group), kc = L>>3 (k-chunk of 4 floats).
__global__ __launch_bounds__(512) void lstm_step(
    const float* __restrict__ Whh, const float* __restrict__ Wih,
    const float* __restrict__ bih, const float* __restrict__ bhh,
    const float* __restrict__ emb, const int* __restrict__ x,
    float* __restrict__ ws, int t)
{
    const int wg    = blockIdx.x;
    const int slice = wg & 31;   // unit slice: units slice*16 .. +16
    const int bg    = wg >> 5;   // batch group 0..7
    const int tid   = threadIdx.x;
    const int w     = tid >> 6;
    const int L     = tid & 63;
    const int b_l   = L & 7;
    const int kc    = L >> 3;
    const int b     = bg * 8 + b_l;

    float* hs  = ws;
    float* cst = ws + C_OFF;

    const float* hprev = hs + (size_t)t * BB * HH + (size_t)b * HH;
    const int    xv    = x[t * BB + b];
    const float* erow  = emb + (size_t)xv * EE;

    float acc[8];
#pragma unroll
    for (int r = 0; r < 8; r++) acc[r] = 0.0f;

    int grow[8];
#pragma unroll
    for (int r = 0; r < 8; r++) {
        int l = w * 8 + r;                         // local gate-row
        grow[r] = (l >> 4) * HH + slice * 16 + (l & 15);  // global row in [0,4H)
    }

    // hh part: k = c*32 + kc*4 + j, c = 0..15
    for (int c = 0; c < 16; c++) {
        const int k0 = c * 32 + kc * 4;
        float4 h4 = *(const float4*)(hprev + k0);
#pragma unroll
        for (int r = 0; r < 8; r++) {
            float4 w4 = *(const float4*)(Whh + (size_t)grow[r] * HH + k0);
            acc[r] += w4.x * h4.x + w4.y * h4.y + w4.z * h4.z + w4.w * h4.w;
        }
    }
    // ih part: e = c*32 + kc*4 + j, c = 0..7 ; embeds scaled by sqrt(E)=16
    for (int c = 0; c < 8; c++) {
        const int k0 = c * 32 + kc * 4;
        float4 e4 = *(const float4*)(erow + k0);
        e4.x *= 16.0f; e4.y *= 16.0f; e4.z *= 16.0f; e4.w *= 16.0f;
#pragma unroll
        for (int r = 0; r < 8; r++) {
            float4 w4 = *(const float4*)(Wih + (size_t)grow[r] * EE + k0);
            acc[r] += w4.x * e4.x + w4.y * e4.y + w4.z * e4.z + w4.w * e4.w;
        }
    }

    // reduce over the 8 kc-lanes (lane bits 3,4,5)
#pragma unroll
    for (int r = 0; r < 8; r++) {
        acc[r] += __shfl_xor(acc[r], 8, 64);
        acc[r] += __shfl_xor(acc[r], 16, 64);
        acc[r] += __shfl_xor(acc[r], 32, 64);
    }

    // lane writes row l = w*8 + kc (static-index select to keep acc in regs)
    float myv = acc[0];
#pragma unroll
    for (int r = 1; r < 8; r++) if (kc == r) myv = acc[r];

    __shared__ float gsm[64][8];
    gsm[w * 8 + kc][b_l] = myv;
    __syncthreads();

    if (tid < 128) {
        const int u  = tid & 15;
        const int bb = tid >> 4;            // 0..7
        const int gu = slice * 16 + u;      // hidden unit index
        float gi = gsm[0 * 16 + u][bb] + bih[0 * HH + gu] + bhh[0 * HH + gu];
        float gf = gsm[1 * 16 + u][bb] + bih[1 * HH + gu] + bhh[1 * HH + gu];
        float gg = gsm[2 * 16 + u][bb] + bih[2 * HH + gu] + bhh[2 * HH + gu];
        float go = gsm[3 * 16 + u][bb] + bih[3 * HH + gu] + bhh[3 * HH + gu];
        float i_ = 1.0f / (1.0f + expf(-gi));
        float f_ = 1.0f / (1.0f + expf(-gf));
        float o_ = 1.0f / (1.0f + expf(-go));
        const int gb = bg * 8 + bb;
        float cc = cst[(size_t)gb * HH + gu];
        float cn = f_ * cc + i_ * tanhf(gg);
        float hn = o_ * tanhf(cn);
        cst[(size_t)gb * HH + gu] = cn;
        hs[(size_t)(t + 1) * BB * HH + (size_t)gb * HH + gu] = hn;
    }
}

// one wave per (t,b): logits = h @ W_out^T + b_out, then log_softmax
__global__ __launch_bounds__(256) void emis_kernel(
    const float* __restrict__ Wout, const float* __restrict__ bout,
    float* __restrict__ ws)
{
    int wid = blockIdx.x * 4 + (threadIdx.x >> 6);  // 0..32767
    int L   = threadIdx.x & 63;
    int t = wid >> 6;
    int b = wid & 63;
    const float* h = ws + (size_t)(t + 1) * BB * HH + (size_t)b * HH;
    float hv[8];
#pragma unroll
    for (int i = 0; i < 8; i++) hv[i] = h[i * 64 + L];
    float acc[9];
#pragma unroll
    for (int tg = 0; tg < 9; tg++) acc[tg] = 0.0f;
    for (int i = 0; i < 8; i++) {
#pragma unroll
        for (int tg = 0; tg < 9; tg++)
            acc[tg] += Wout[tg * HH + i * 64 + L] * hv[i];
    }
#pragma unroll
    for (int tg = 0; tg < 9; tg++) {
        acc[tg] += __shfl_xor(acc[tg], 1, 64);
        acc[tg] += __shfl_xor(acc[tg], 2, 64);
        acc[tg] += __shfl_xor(acc[tg], 4, 64);
        acc[tg] += __shfl_xor(acc[tg], 8, 64);
        acc[tg] += __shfl_xor(acc[tg], 16, 64);
        acc[tg] += __shfl_xor(acc[tg], 32, 64);
    }
    float lg[9];
#pragma unroll
    for (int tg = 0; tg < 9; tg++) lg[tg] = acc[tg] + bout[tg];
    float m = lg[0];
#pragma unroll
    for (int tg = 1; tg < 9; tg++) m = fmaxf(m, lg[tg]);
    float ssum = 0.0f;
#pragma unroll
    for (int tg = 0; tg < 9; tg++) ssum += expf(lg[tg] - m);
    float lse = m + logf(ssum);
    float myo = lg[0] - lse;
#pragma unroll
    for (int tg = 1; tg < 9; tg++) if (L == tg) myo = lg[tg] - lse;
    if (L < 9) ws[EM_OFF + (size_t)wid * 9 + L] = myo;
}

// numerator of CRF llh, one thread per batch element
__global__ __launch_bounds__(64) void crf_num(
    const int* __restrict__ x, const int* __restrict__ bio,
    const float* __restrict__ start_t, const float* __restrict__ end_t,
    const float* __restrict__ trans, float* __restrict__ ws)
{
    int b = threadIdx.x;
    const float* em = ws + EM_OFF;
    int prev = bio[b];
    float num = start_t[prev] + em[(size_t)b * 9 + prev];
    int cnt = (x[b] != 0) ? 1 : 0;
    for (int s = 1; s < SS; s++) {
        int tg = bio[s * BB + b];
        float mk = (x[s * BB + b] != 0) ? 1.0f : 0.0f;
        num += (em[((size_t)s * BB + b) * 9 + tg] + trans[prev * 9 + tg]) * mk;
        cnt += (x[s * BB + b] != 0) ? 1 : 0;
        prev = tg;
    }
    int se = cnt - 1;
    int lastt = bio[se * BB + b];
    num += end_t[lastt];
    ws[NUM_OFF + b] = num;
}

// CRF forward (log-partition). 8 WGs x 128 thr: thread = (j = tid>>3, b_l = tid&7)
__global__ __launch_bounds__(128) void crf_fwd(
    const int* __restrict__ x,
    const float* __restrict__ start_t, const float* __restrict__ end_t,
    const float* __restrict__ trans, float* __restrict__ ws)
{
    const float* em = ws + EM_OFF;
    int b_l = threadIdx.x & 7;
    int j   = threadIdx.x >> 3;       // 0..15, active j<9
    int b   = blockIdx.x * 8 + b_l;
    __shared__ float sc[9][8];
    float tc[9];
    if (j < 9) {
#pragma unroll
        for (int i = 0; i < 9; i++) tc[i] = trans[i * 9 + j];
        sc[j][b_l] = start_t[j] + em[(size_t)b * 9 + j];
    }
    __syncthreads();
    for (int s = 1; s < SS; s++) {
        float nv = 0.0f;
        if (j < 9) {
            float sv[9];
            float m = -3.4e38f;
#pragma unroll
            for (int i = 0; i < 9; i++) {
                sv[i] = sc[i][b_l] + tc[i];
                m = fmaxf(m, sv[i]);
            }
            float ssum = 0.0f;
#pragma unroll
            for (int i = 0; i < 9; i++) ssum += expf(sv[i] - m);
            nv = m + logf(ssum) + em[((size_t)s * BB + b) * 9 + j];
        }
        bool mk = (x[s * BB + b] != 0);
        __syncthreads();
        if (j < 9 && mk) sc[j][b_l] = nv;
        __syncthreads();
    }
    if (j == 0) {
        float m = -3.4e38f;
#pragma unroll
        for (int i = 0; i < 9; i++) m = fmaxf(m, sc[i][b_l] + end_t[i]);
        float ssum = 0.0f;
#pragma unroll
        for (int i = 0; i < 9; i++) ssum += expf(sc[i][b_l] + end_t[i] - m);
        ws[NORM_OFF + b] = m + logf(ssum);
    }
}

// Viterbi: forward max-product with in-LDS history + backtrace. 8 WGs x 128 thr.
__global__ __launch_bounds__(128) void viterbi_kernel(
    const float* __restrict__ start_t, const float* __restrict__ end_t,
    const float* __restrict__ trans, const float* __restrict__ ws,
    float* __restrict__ out)
{
    const float* em = ws + EM_OFF;
    int b_l = threadIdx.x & 7;
    int j   = threadIdx.x >> 3;
    int b   = blockIdx.x * 8 + b_l;
    __shared__ float sc[9][8];
    __shared__ unsigned char hist[SS - 1][8][9];   // 36792 B
    float tc[9];
    if (j < 9) {
#pragma unroll
        for (int i = 0; i < 9; i++) tc[i] = trans[i * 9 + j];
        sc[j][b_l] = start_t[j] + em[(size_t)b * 9 + j];
    }
    __syncthreads();
    for (int s = 1; s < SS; s++) {
        float nv = 0.0f;
        if (j < 9) {
            float best = sc[0][b_l] + tc[0];
            int bi = 0;
#pragma unroll
            for (int i = 1; i < 9; i++) {
                float v = sc[i][b_l] + tc[i];
                if (v > best) { best = v; bi = i; }   // strict >: first max, matches jnp.argmax
            }
            hist[s - 1][b_l][j] = (unsigned char)bi;
            nv = best + em[((size_t)s * BB + b) * 9 + j];
        }
        __syncthreads();
        if (j < 9) sc[j][b_l] = nv;
        __syncthreads();
    }
    if (threadIdx.x < 8) {
        int bl = threadIdx.x;
        int gb = blockIdx.x * 8 + bl;
        float best = sc[0][bl] + end_t[0];
        int cur = 0;
#pragma unroll
        for (int i = 1; i < 9; i++) {
            float v = sc[i][bl] + end_t[i];
            if (v > best) { best = v; cur = i; }
        }
        out[1 + (size_t)(SS - 1) * BB + gb] = (float)cur;
        for (int s = SS - 2; s >= 0; s--) {
            cur = hist[s][bl][cur];
            out[1 + (size_t)s * BB + gb] = (float)cur;
        }
    }
}

__global__ __launch_bounds__(64) void final_llh(const float* __restrict__ ws,
                                               float* __restrict__ out)
{
    int L = threadIdx.x;
    float v = ws[NUM_OFF + L] - ws[NORM_OFF + L];
    v += __shfl_xor(v, 1, 64);
    v += __shfl_xor(v, 2, 64);
    v += __shfl_xor(v, 4, 64);
    v += __shfl_xor(v, 8, 64);
    v += __shfl_xor(v, 16, 64);
    v += __shfl_xor(v, 32, 64);
    if (L == 0) out[0] = -v;
}

extern "C" void kernel_launch(void* const* d_in, const int* in_sizes, int n_in,
                              void* d_out, int out_size, void* d_ws, size_t ws_size,
                              hipStream_t stream) {
    const int*   x       = (const int*)d_in[0];
    const int*   bio     = (const int*)d_in[1];
    const float* emb     = (const float*)d_in[2];
    const float* W_ih    = (const float*)d_in[3];
    const float* W_hh    = (const float*)d_in[4];
    const float* b_ih    = (const float*)d_in[5];
    const float* b_hh    = (const float*)d_in[6];
    const float* W_out   = (const float*)d_in[7];
    const float* b_out   = (const float*)d_in[8];
    const float* start_t = (const float*)d_in[9];
    const float* end_t   = (const float*)d_in[10];
    const float* trans   = (const float*)d_in[11];
    float* out = (float*)d_out;
    float* ws  = (float*)d_ws;

    init_state<<<256, 256, 0, stream>>>(ws);
    for (int t = 0; t < SS; t++) {
        lstm_step<<<256, 512, 0, stream>>>(W_hh, W_ih, b_ih, b_hh, emb, x, ws, t);
    }
    emis_kernel<<<SS * BB / 4, 256, 0, stream>>>(W_out, b_out, ws);
    crf_num<<<1, 64, 0, stream>>>(x, bio, start_t, end_t, trans, ws);
    crf_fwd<<<8, 128, 0, stream>>>(x, start_t, end_t, trans, ws);
    viterbi_kernel<<<8, 128, 0, stream>>>(start_t, end_t, trans, ws, out);
    final_llh<<<1, 64, 0, stream>>>(ws, out);
}